// Round 5
// baseline (370.422 us; speedup 1.0000x reference)
//
#include <hip/hip_runtime.h>
#include <cstdint>

#define S_ 197
#define D_ 768
#define H_ 12
#define B_ 2
#define SS_ (S_*S_)

// ---- output offsets (floats), concat in reference return order ----
#define O_WN   0          // (B,H,S,S)  931416
#define O_SN   931416     // (B,S,S)    77618
#define O_RWN  1009034
#define O_PLNN 1086652
#define O_PLN  1164270    // (B,S,S,D)  59610624
#define O_AM   60774894   // (B,S) 394
#define O_ARM  60775288
#define O_ARLM 60775682

// ---- workspace offsets (floats) ----
// Layout (high-water 4,849,352 floats < previous 5,134,614):
//   [T2 3631104][TN 4728][ACC 1210368 (WT overlaid: dead before ACC written)]
//   [SMU 1576][MUI 394][P3 1182]
#define WS_T2   0
#define WS_TN   3631104
#define WS_ACC  3635832
#define WS_WT   3635832    // overlay: kTranspose writes, kTransform reads, then dead
#define WS_SMU  4846200
#define WS_MUI  4847776
#define WS_P3   4848170

#define I_T 4      // i-values per main block
#define NC 4       // j chunks: widths 50,50,49,48 (bounds 0,50,100,149,197)
#define JCM 50     // max chunk width (LDS stride)

__device__ __forceinline__ float wred64(float v) {
#pragma unroll
  for (int off = 32; off > 0; off >>= 1) v += __shfl_xor(v, off);
  return v;
}

__device__ __forceinline__ void load12(const float* __restrict__ p, float t[12]) {
  const float4* q = (const float4*)p;
  float4 a = q[0], b = q[1], c = q[2];
  t[0]=a.x; t[1]=a.y; t[2]=a.z; t[3]=a.w;
  t[4]=b.x; t[5]=b.y; t[6]=b.z; t[7]=b.w;
  t[8]=c.x; t[9]=c.y; t[10]=c.z; t[11]=c.w;
}

// ---------------- W transpose: Wt[c][d] = W[d][c] (768x768) ----------------
__global__ __launch_bounds__(256) void kTranspose(const float* __restrict__ in,
                                                  float* __restrict__ outp) {
  __shared__ float tile[32][33];
  int x = blockIdx.x*32 + threadIdx.x;
  int y = blockIdx.y*32 + threadIdx.y;
#pragma unroll
  for (int k = 0; k < 32; k += 8) tile[threadIdx.y+k][threadIdx.x] = in[(y+k)*D_ + x];
  __syncthreads();
  x = blockIdx.y*32 + threadIdx.x;
  y = blockIdx.x*32 + threadIdx.y;
#pragma unroll
  for (int k = 0; k < 32; k += 8) outp[(y+k)*D_ + x] = tile[threadIdx.x][threadIdx.y+k];
}

// ------------- T2[b][s][h][d] = sum_v V[b,h,s,v]*W[d,h*64+v]; tnorm -------------
#define TST 8
__global__ __launch_bounds__(256) void kTransform(const float* __restrict__ V,
                                                  const float* __restrict__ Wt,
                                                  float* __restrict__ T2,
                                                  float* __restrict__ tnorm) {
  int blk = blockIdx.x;             // 600 = 8*75
  int xcd = blk & 7; int slot = blk >> 3;   // slot 0..74
  int bh = xcd*3 + (slot % 3);              // 0..23
  int st = slot / 3;                        // 0..24
  int h = bh % H_; int b = bh / H_;
  int s0 = st*TST; int ns = min(TST, S_ - s0);
  __shared__ float vt[TST*64];
  __shared__ float red[4][TST];
  int t = threadIdx.x;
  const float* Vbase = V + ((size_t)bh*S_ + s0)*64;
  for (int e = t; e < ns*64; e += 256) vt[e] = Vbase[e];
  __syncthreads();
  float acc2[TST];
#pragma unroll
  for (int s = 0; s < TST; s++) acc2[s] = 0.f;
  for (int g = 0; g < 3; g++) {
    int d = t + g*256;
    float acc[TST];
#pragma unroll
    for (int s = 0; s < TST; s++) acc[s] = 0.f;
    const float* wp = Wt + (size_t)h*64*D_ + d;
#pragma unroll 8
    for (int v = 0; v < 64; v++) {
      float wv = wp[(size_t)v*D_];
#pragma unroll
      for (int s = 0; s < TST; s++) acc[s] = fmaf(vt[s*64+v], wv, acc[s]);
    }
    for (int s = 0; s < ns; s++) {
      T2[((size_t)(b*S_ + s0+s)*H_ + h)*D_ + d] = acc[s];
      acc2[s] = fmaf(acc[s], acc[s], acc2[s]);
    }
  }
  int lane = t & 63, wq = t >> 6;
#pragma unroll
  for (int s = 0; s < TST; s++) {
    float v = wred64(acc2[s]);
    if (lane == 0) red[wq][s] = v;
  }
  __syncthreads();
  if (t < ns) {
    float v = red[0][t] + red[1][t] + red[2][t] + red[3][t];
    tnorm[bh*S_ + s0 + t] = sqrtf(v);
  }
}

// ------------- main fused kernel -------------
// 512 threads (8 waves), grid 400 = 8 XCD * 50 i-tiles.
// xcd (blk&7) <-> (b,c) combo 1:1: per-XCD T2 slice ~1.8 MB, L2-resident.
// 2 blocks/CU co-resident (16 waves/CU = VGPR-84 cap) on 144 CUs, all 256 busy
// (old: 200 blocks x 12 waves -> 56 CUs idle, 12 waves/CU).
// weighted_norm fused here (attn already in LDS); diag vector replaced by 3
// scalars (ls2/lrw2/q ARE pS/pRW/pP at the diagonal).
__global__ __launch_bounds__(512) void kMain(const float* __restrict__ attn,
                                             const float* __restrict__ hs,
                                             const float* __restrict__ lnw,
                                             const float* __restrict__ preln,
                                             const float* __restrict__ T2,
                                             const float* __restrict__ tnorm,
                                             float* __restrict__ outp,
                                             float* __restrict__ wsAccS,
                                             float* __restrict__ wsSmu,
                                             float* __restrict__ wsMui,
                                             float* __restrict__ wsP) {
  int blk = blockIdx.x;
  int xcd = blk & 7; int it = blk >> 3;     // it 0..49
  int b = xcd >> 2;  int c = xcd & 3;
  int i0 = it * I_T;
  int jc0 = (c == 3) ? 149 : c*50;
  int jcE = (c == 0) ? 50 : (c == 1) ? 100 : (c == 2) ? 149 : 197;
  int jcW = jcE - jc0;
  int ni = min(I_T, S_ - i0);
  int tid = threadIdx.x;
  int lane = tid & 63, wv = tid >> 6;       // wv 0..7
  int dbase = lane * 12;

  __shared__ float ash[H_*I_T*JCM];   // [h][i][jj]
  __shared__ float tnl[H_*JCM];       // [h][jj]
  __shared__ float sAcc[I_T*D_];
  __shared__ float sSmu[8*I_T];

  // preload attention coefficients (coalesced over jj)
  int tot = H_*I_T*jcW;
  for (int e = tid; e < tot; e += 512) {
    int hh = e / (I_T*jcW); int rem = e - hh*(I_T*jcW);
    int ii = rem / jcW; int jj = rem - ii*jcW;
    int iG = i0 + ii;
    float v = 0.f;
    if (iG < S_) v = attn[((size_t)(b*H_ + hh)*S_ + iG)*S_ + (jc0 + jj)];
    ash[(hh*I_T + ii)*JCM + jj] = v;
  }
  // preload tnorm tile for fused weighted_norm
  for (int e = tid; e < H_*jcW; e += 512) {
    int hh = e / jcW; int jj = e - hh*jcW;
    tnl[hh*JCM + jj] = tnorm[(b*H_ + hh)*S_ + jc0 + jj];
  }

  // per-lane setup
  float w_[12];
  load12(lnw + dbase, w_);
  float w2s_l = 0.f;
#pragma unroll
  for (int m = 0; m < 12; m++) w2s_l = fmaf(w_[m], w_[m], w2s_l);
  float w2sum = wred64(w2s_l);

  float istd[I_T];
#pragma unroll
  for (int ii = 0; ii < I_T; ii++) {
    int iG = i0 + ii;
    istd[ii] = 0.f;
    if (iG < S_) {
      float x[12];
      load12(preln + (size_t)(b*S_ + iG)*D_ + dbase, x);
      float sx = 0.f, sx2 = 0.f;
#pragma unroll
      for (int m = 0; m < 12; m++) { sx += x[m]; sx2 = fmaf(x[m], x[m], sx2); }
      sx = wred64(sx); sx2 = wred64(sx2);
      float mu = sx * (1.0f/768.0f);
      float var = sx2 * (1.0f/768.0f) - mu*mu;
      istd[ii] = 1.0f / sqrtf(var + 1e-12f);
    }
  }

  float accS[I_T][12];
#pragma unroll
  for (int ii = 0; ii < I_T; ii++)
#pragma unroll
    for (int m = 0; m < 12; m++) accS[ii][m] = 0.f;
  float smu[I_T] = {0.f, 0.f, 0.f, 0.f};

  __syncthreads();

  for (int j = jc0 + wv; j < jcE; j += 8) {
    int jj = j - jc0;
    const float* tb = T2 + (size_t)(b*S_ + j)*H_*D_ + dbase;
    float s[I_T][12];
#pragma unroll
    for (int ii = 0; ii < I_T; ii++)
#pragma unroll
      for (int m = 0; m < 12; m++) s[ii][m] = 0.f;
#pragma unroll 2
    for (int h = 0; h < H_; h++) {
      float t[12];
      load12(tb + h*D_, t);
#pragma unroll
      for (int ii = 0; ii < I_T; ii++) {
        float ah = ash[(h*I_T + ii)*JCM + jj];
#pragma unroll
        for (int m = 0; m < 12; m++) s[ii][m] = fmaf(ah, t[m], s[ii][m]);
      }
    }
#pragma unroll
    for (int ii = 0; ii < I_T; ii++) {
      int iG = i0 + ii;
      if (iG < S_) {
        bool isDiag = (j == iG);
        float rw[12];
        if (isDiag) {
          float hh[12];
          load12(hs + (size_t)(b*S_ + iG)*D_ + dbase, hh);
#pragma unroll
          for (int m = 0; m < 12; m++) rw[m] = s[ii][m] + hh[m];
        } else {
#pragma unroll
          for (int m = 0; m < 12; m++) rw[m] = s[ii][m];
        }
        float ls2 = 0.f, lrw = 0.f, lrw2 = 0.f, lrww2 = 0.f, lrw2w2 = 0.f;
#pragma unroll
        for (int m = 0; m < 12; m++) {
          ls2 = fmaf(s[ii][m], s[ii][m], ls2);
          lrw += rw[m];
          float t1 = rw[m] * w_[m];
          lrww2 = fmaf(t1, w_[m], lrww2);
          lrw2 = fmaf(rw[m], rw[m], lrw2);
          lrw2w2 = fmaf(t1, t1, lrw2w2);
        }
        ls2 = wred64(ls2); lrw = wred64(lrw); lrw2 = wred64(lrw2);
        lrww2 = wred64(lrww2); lrw2w2 = wred64(lrw2w2);
        float mu = lrw * (1.0f/768.0f);
        float q = fmaf(mu*mu, w2sum, fmaf(-2.0f*mu, lrww2, lrw2w2));
        q = fmaxf(q, 0.f);
        float plnn = istd[ii] * sqrtf(q);
        int oIdx = (b*S_ + iG)*S_ + j;
        if (lane == 0) {
          outp[O_SN + oIdx] = sqrtf(ls2);
          outp[O_RWN + oIdx] = sqrtf(lrw2);
          outp[O_PLNN + oIdx] = plnn;
        }
        // post_ln write: base is ==8 mod 16 bytes -> peel 2 + 4 + 4 + 2 (cached).
        float* po = outp + O_PLN + (size_t)oIdx*D_ + dbase;
        float a = istd[ii];
        float p[12];
#pragma unroll
        for (int m = 0; m < 12; m++) p[m] = (rw[m] - mu) * a * w_[m];
        *(float2*)po        = make_float2(p[0], p[1]);
        *(float4*)(po + 2)  = make_float4(p[2], p[3], p[4], p[5]);
        *(float4*)(po + 6)  = make_float4(p[6], p[7], p[8], p[9]);
        *(float2*)(po + 10) = make_float2(p[10], p[11]);
        smu[ii] += mu;
        if (isDiag) {
          // Skip accS add (mixing excludes the diagonal); store the 3
          // preserving-norm scalars: ls2 == |diag s|^2, lrw2 == |diag rw|^2,
          // q == |w*(rw-mu)|^2 (post_ln diag, istd factored out).
          if (lane == 0) {
            wsMui[b*S_ + iG] = mu;
            wsP[(b*S_ + iG)*3 + 0] = ls2;
            wsP[(b*S_ + iG)*3 + 1] = lrw2;
            wsP[(b*S_ + iG)*3 + 2] = q;
          }
        } else {
#pragma unroll
          for (int m = 0; m < 12; m++) accS[ii][m] += s[ii][m];
        }
      }
    }
  }

  // combine per-wave accumulators
  if (lane == 0) {
#pragma unroll
    for (int ii = 0; ii < I_T; ii++) sSmu[wv*I_T + ii] = smu[ii];
  }
  for (int rr = 0; rr < 8; rr++) {
    __syncthreads();
    if (wv == rr) {
#pragma unroll
      for (int ii = 0; ii < I_T; ii++) {
        if (ii < ni) {
#pragma unroll
          for (int m = 0; m < 12; m++) {
            int a = ii*D_ + dbase + m;
            sAcc[a] = (rr == 0) ? accS[ii][m] : (sAcc[a] + accS[ii][m]);
          }
        }
      }
    }
  }
  __syncthreads();
  for (int e = tid; e < ni*192; e += 512) {
    int ii = e / 192; int d4 = (e % 192) * 4;
    float4 v = *(float4*)&sAcc[ii*D_ + d4];
    *(float4*)(wsAccS + (size_t)((b*S_ + i0 + ii)*NC + c)*D_ + d4) = v;
  }
  if (tid < ni) {
    float ss = 0.f;
#pragma unroll
    for (int wq = 0; wq < 8; wq++) ss += sSmu[wq*I_T + tid];
    wsSmu[(b*S_ + i0 + tid)*NC + c] = ss;
  }
  // fused weighted_norm = |attn| * tnorm (all inputs in LDS)
  int totW = H_*ni*jcW;
  for (int e = tid; e < totW; e += 512) {
    int hh = e / (ni*jcW); int rem = e - hh*(ni*jcW);
    int ii = rem / jcW; int jj = rem - ii*jcW;
    int iG = i0 + ii;
    outp[O_WN + ((size_t)(b*H_ + hh)*S_ + iG)*S_ + jc0 + jj] =
        fabsf(ash[(hh*I_T + ii)*JCM + jj]) * tnl[hh*JCM + jj];
  }
}

// ------------- mixing-ratio finalization -------------
__global__ __launch_bounds__(256) void kMixing(const float* __restrict__ wsAccS,
                                               const float* __restrict__ wsSmu,
                                               const float* __restrict__ wsMui,
                                               const float* __restrict__ wsP,
                                               const float* __restrict__ lnw,
                                               float* __restrict__ outp) {
  int bi = blockIdx.x;   // b*197 + i
  int t = threadIdx.x;
  float Smu = wsSmu[bi*4] + wsSmu[bi*4+1] + wsSmu[bi*4+2] + wsSmu[bi*4+3];
  float mui = wsMui[bi];
  float dmu = Smu - mui;
  float mS = 0.f, mP = 0.f;
#pragma unroll
  for (int g = 0; g < 3; g++) {
    int d = t + g*256;
    float mix = wsAccS[((size_t)bi*4 + 0)*D_ + d] + wsAccS[((size_t)bi*4 + 1)*D_ + d]
              + wsAccS[((size_t)bi*4 + 2)*D_ + d] + wsAccS[((size_t)bi*4 + 3)*D_ + d];
    float w = lnw[d];
    mS = fmaf(mix, mix, mS);
    float mp = w * (mix - dmu);
    mP = fmaf(mp, mp, mP);
  }
  __shared__ float red[4][2];
  int lane = t & 63, wv = t >> 6;
  mS = wred64(mS); mP = wred64(mP);
  if (lane == 0) { red[wv][0] = mS; red[wv][1] = mP; }
  __syncthreads();
  if (t == 0) {
    float a0 = 0.f, a1 = 0.f;
#pragma unroll
    for (int k = 0; k < 4; k++) { a0 += red[k][0]; a1 += red[k][1]; }
    float mn = sqrtf(a0), mnp = sqrtf(a1);
    float pn   = sqrtf(wsP[bi*3 + 0]);
    float pnrw = sqrtf(wsP[bi*3 + 1]);
    float pnp  = sqrtf(wsP[bi*3 + 2]);
    outp[O_AM   + bi] = mn / (mn + pn);
    outp[O_ARM  + bi] = mn / (mn + pnrw);
    outp[O_ARLM + bi] = mnp / (mnp + pnp);
  }
}

extern "C" void kernel_launch(void* const* d_in, const int* in_sizes, int n_in,
                              void* d_out, int out_size, void* d_ws, size_t ws_size,
                              hipStream_t stream) {
  const float* hs    = (const float*)d_in[0];
  const float* attn  = (const float*)d_in[1];
  const float* V     = (const float*)d_in[2];
  const float* W     = (const float*)d_in[3];
  const float* lnw   = (const float*)d_in[4];
  const float* preln = (const float*)d_in[5];
  float* out = (float*)d_out;
  float* ws  = (float*)d_ws;

  kTranspose<<<dim3(24,24), dim3(32,8), 0, stream>>>(W, ws + WS_WT);
  kTransform<<<dim3(600), dim3(256), 0, stream>>>(V, ws + WS_WT, ws + WS_T2, ws + WS_TN);
  kMain<<<dim3(400), dim3(512), 0, stream>>>(attn, hs, lnw, preln, ws + WS_T2, ws + WS_TN,
                                             out, ws + WS_ACC, ws + WS_SMU, ws + WS_MUI, ws + WS_P3);
  kMixing<<<dim3(B_*S_), dim3(256), 0, stream>>>(ws + WS_ACC, ws + WS_SMU, ws + WS_MUI, ws + WS_P3,
                                                 lnw, out);
}

// Round 6
// 347.227 us; speedup vs baseline: 1.0668x; 1.0668x over previous
//
#include <hip/hip_runtime.h>
#include <cstdint>

#define S_ 197
#define D_ 768
#define H_ 12
#define B_ 2
#define SS_ (S_*S_)

// ---- output offsets (floats), concat in reference return order ----
#define O_WN   0          // (B,H,S,S)  931416
#define O_SN   931416     // (B,S,S)    77618
#define O_RWN  1009034
#define O_PLNN 1086652
#define O_PLN  1164270    // (B,S,S,D)  59610624
#define O_AM   60774894   // (B,S) 394
#define O_ARM  60775288
#define O_ARLM 60775682

// ---- workspace offsets (floats), high-water 4,243,380 ----
#define WS_T2   0          // T2[b][j][h][d]  3631104
#define WS_TN   3631104    // tnorm           4728
#define WS_ACC  3635832    // accS[b][i][c][d] 605184 (NC=2)
#define WS_WT   3635832    // WT overlay: dead before ACC is written
#define WS_SMU  4241016    // 788
#define WS_MUI  4241804    // 394
#define WS_P3   4242198    // 1182

#define I_T 4      // i-values per main block
#define NIT 50     // ceil(197/4)
#define NC 2       // j chunks
#define JC 99      // chunk width (c0: 99, c1: 98)

__device__ __forceinline__ float wred64(float v) {
#pragma unroll
  for (int off = 32; off > 0; off >>= 1) v += __shfl_xor(v, off);
  return v;
}

__device__ __forceinline__ void load12(const float* __restrict__ p, float t[12]) {
  const float4* q = (const float4*)p;
  float4 a = q[0], b = q[1], c = q[2];
  t[0]=a.x; t[1]=a.y; t[2]=a.z; t[3]=a.w;
  t[4]=b.x; t[5]=b.y; t[6]=b.z; t[7]=b.w;
  t[8]=c.x; t[9]=c.y; t[10]=c.z; t[11]=c.w;
}

// ---------------- W transpose: Wt[c][d] = W[d][c] (768x768) ----------------
__global__ __launch_bounds__(256) void kTranspose(const float* __restrict__ in,
                                                  float* __restrict__ outp) {
  __shared__ float tile[32][33];
  int x = blockIdx.x*32 + threadIdx.x;
  int y = blockIdx.y*32 + threadIdx.y;
#pragma unroll
  for (int k = 0; k < 32; k += 8) tile[threadIdx.y+k][threadIdx.x] = in[(y+k)*D_ + x];
  __syncthreads();
  x = blockIdx.y*32 + threadIdx.x;
  y = blockIdx.x*32 + threadIdx.y;
#pragma unroll
  for (int k = 0; k < 32; k += 8) outp[(y+k)*D_ + x] = tile[threadIdx.x][threadIdx.y+k];
}

// ------------- T2[b][s][h][d] = sum_v V[b,h,s,v]*W[d,h*64+v]; tnorm -------------
#define TST 8
__global__ __launch_bounds__(256) void kTransform(const float* __restrict__ V,
                                                  const float* __restrict__ Wt,
                                                  float* __restrict__ T2,
                                                  float* __restrict__ tnorm) {
  int blk = blockIdx.x;             // 600 = 8*75
  int xcd = blk & 7; int slot = blk >> 3;   // slot 0..74
  int bh = xcd*3 + (slot % 3);              // 0..23
  int st = slot / 3;                        // 0..24
  int h = bh % H_; int b = bh / H_;
  int s0 = st*TST; int ns = min(TST, S_ - s0);
  __shared__ float vt[TST*64];
  __shared__ float red[4][TST];
  int t = threadIdx.x;
  const float* Vbase = V + ((size_t)bh*S_ + s0)*64;
  for (int e = t; e < ns*64; e += 256) vt[e] = Vbase[e];
  __syncthreads();
  float acc2[TST];
#pragma unroll
  for (int s = 0; s < TST; s++) acc2[s] = 0.f;
  for (int g = 0; g < 3; g++) {
    int d = t + g*256;
    float acc[TST];
#pragma unroll
    for (int s = 0; s < TST; s++) acc[s] = 0.f;
    const float* wp = Wt + (size_t)h*64*D_ + d;
#pragma unroll 8
    for (int v = 0; v < 64; v++) {
      float wv = wp[(size_t)v*D_];
#pragma unroll
      for (int s = 0; s < TST; s++) acc[s] = fmaf(vt[s*64+v], wv, acc[s]);
    }
    for (int s = 0; s < ns; s++) {
      T2[((size_t)(b*S_ + s0+s)*H_ + h)*D_ + d] = acc[s];
      acc2[s] = fmaf(acc[s], acc[s], acc2[s]);
    }
  }
  int lane = t & 63, wq = t >> 6;
#pragma unroll
  for (int s = 0; s < TST; s++) {
    float v = wred64(acc2[s]);
    if (lane == 0) red[wq][s] = v;
  }
  __syncthreads();
  if (t < ns) {
    float v = red[0][t] + red[1][t] + red[2][t] + red[3][t];
    tnorm[bh*S_ + s0 + t] = sqrtf(v);
  }
}

// ------------- main fused kernel -------------
// PROVEN R4 structure: 768 threads (12 waves), grid 200 = 8 XCD * 25; each
// XCD-pair owns one (b,c) combo -> per-XCD T2 slice 3.6 MB, L2-resident.
// (R5's 512-thread/400-block rebalance regressed +19 us: 1.56 blocks/CU
// quantization -> 144 CUs serialize 2 blocks; do not repeat.)
// Grafts kept from R5 (work-removal only):
//  - weighted_norm fused into epilogue (attn already in LDS; no extra kernel)
//  - diag vector replaced by 3 scalars (ls2/lrw2/q ARE pS/pRW/pP at diagonal)
// post_ln uses cached stores (NT stores caused 2.4x write amplification, R3).
__global__ __launch_bounds__(768) void kMain(const float* __restrict__ attn,
                                             const float* __restrict__ hs,
                                             const float* __restrict__ lnw,
                                             const float* __restrict__ preln,
                                             const float* __restrict__ T2,
                                             const float* __restrict__ tnorm,
                                             float* __restrict__ outp,
                                             float* __restrict__ wsAccS,
                                             float* __restrict__ wsSmu,
                                             float* __restrict__ wsMui,
                                             float* __restrict__ wsP) {
  int blk = blockIdx.x;
  int xcd = blk & 7; int slot = blk >> 3;   // slot 0..24
  int b = (xcd >> 2) & 1;
  int c = (xcd >> 1) & 1;
  int it = slot*2 + (xcd & 1);              // 0..49
  int i0 = it * I_T;
  int jc0 = c * JC;
  int jcE = min(jc0 + JC, S_);
  int jcW = jcE - jc0;
  int ni = min(I_T, S_ - i0);
  int tid = threadIdx.x;
  int lane = tid & 63, wv = tid >> 6;
  int dbase = lane * 12;

  __shared__ float ash[H_*I_T*JC];    // [h][i][jj]
  __shared__ float tnl[H_*JC];        // [h][jj]
  __shared__ float sAcc[I_T*D_];
  __shared__ float sSmu[12*I_T];

  // preload attention coefficients (coalesced over jj)
  int tot = H_*I_T*jcW;
  for (int e = tid; e < tot; e += 768) {
    int hh = e / (I_T*jcW); int rem = e - hh*(I_T*jcW);
    int ii = rem / jcW; int jj = rem - ii*jcW;
    int iG = i0 + ii;
    float v = 0.f;
    if (iG < S_) v = attn[((size_t)(b*H_ + hh)*S_ + iG)*S_ + (jc0 + jj)];
    ash[(hh*I_T + ii)*JC + jj] = v;
  }
  // preload tnorm tile for fused weighted_norm
  for (int e = tid; e < H_*jcW; e += 768) {
    int hh = e / jcW; int jj = e - hh*jcW;
    tnl[hh*JC + jj] = tnorm[(b*H_ + hh)*S_ + jc0 + jj];
  }

  // per-lane setup
  float w_[12];
  load12(lnw + dbase, w_);
  float w2s_l = 0.f;
#pragma unroll
  for (int m = 0; m < 12; m++) w2s_l = fmaf(w_[m], w_[m], w2s_l);
  float w2sum = wred64(w2s_l);

  float istd[I_T];
#pragma unroll
  for (int ii = 0; ii < I_T; ii++) {
    int iG = i0 + ii;
    istd[ii] = 0.f;
    if (iG < S_) {
      float x[12];
      load12(preln + (size_t)(b*S_ + iG)*D_ + dbase, x);
      float sx = 0.f, sx2 = 0.f;
#pragma unroll
      for (int m = 0; m < 12; m++) { sx += x[m]; sx2 = fmaf(x[m], x[m], sx2); }
      sx = wred64(sx); sx2 = wred64(sx2);
      float mu = sx * (1.0f/768.0f);
      float var = sx2 * (1.0f/768.0f) - mu*mu;
      istd[ii] = 1.0f / sqrtf(var + 1e-12f);
    }
  }

  float accS[I_T][12];
#pragma unroll
  for (int ii = 0; ii < I_T; ii++)
#pragma unroll
    for (int m = 0; m < 12; m++) accS[ii][m] = 0.f;
  float smu[I_T] = {0.f, 0.f, 0.f, 0.f};

  __syncthreads();

  for (int j = jc0 + wv; j < jcE; j += 12) {
    int jj = j - jc0;
    const float* tb = T2 + (size_t)(b*S_ + j)*H_*D_ + dbase;
    float s[I_T][12];
#pragma unroll
    for (int ii = 0; ii < I_T; ii++)
#pragma unroll
      for (int m = 0; m < 12; m++) s[ii][m] = 0.f;
#pragma unroll 2
    for (int h = 0; h < H_; h++) {
      float t[12];
      load12(tb + h*D_, t);
#pragma unroll
      for (int ii = 0; ii < I_T; ii++) {
        float ah = ash[(h*I_T + ii)*JC + jj];
#pragma unroll
        for (int m = 0; m < 12; m++) s[ii][m] = fmaf(ah, t[m], s[ii][m]);
      }
    }
#pragma unroll
    for (int ii = 0; ii < I_T; ii++) {
      int iG = i0 + ii;
      if (iG < S_) {
        bool isDiag = (j == iG);
        float rw[12];
        if (isDiag) {
          float hh[12];
          load12(hs + (size_t)(b*S_ + iG)*D_ + dbase, hh);
#pragma unroll
          for (int m = 0; m < 12; m++) rw[m] = s[ii][m] + hh[m];
        } else {
#pragma unroll
          for (int m = 0; m < 12; m++) rw[m] = s[ii][m];
        }
        float ls2 = 0.f, lrw = 0.f, lrw2 = 0.f, lrww2 = 0.f, lrw2w2 = 0.f;
#pragma unroll
        for (int m = 0; m < 12; m++) {
          ls2 = fmaf(s[ii][m], s[ii][m], ls2);
          lrw += rw[m];
          float t1 = rw[m] * w_[m];
          lrww2 = fmaf(t1, w_[m], lrww2);
          lrw2 = fmaf(rw[m], rw[m], lrw2);
          lrw2w2 = fmaf(t1, t1, lrw2w2);
        }
        ls2 = wred64(ls2); lrw = wred64(lrw); lrw2 = wred64(lrw2);
        lrww2 = wred64(lrww2); lrw2w2 = wred64(lrw2w2);
        float mu = lrw * (1.0f/768.0f);
        float q = fmaf(mu*mu, w2sum, fmaf(-2.0f*mu, lrww2, lrw2w2));
        q = fmaxf(q, 0.f);
        float plnn = istd[ii] * sqrtf(q);
        int oIdx = (b*S_ + iG)*S_ + j;
        if (lane == 0) {
          outp[O_SN + oIdx] = sqrtf(ls2);
          outp[O_RWN + oIdx] = sqrtf(lrw2);
          outp[O_PLNN + oIdx] = plnn;
        }
        // post_ln write: base is ==8 mod 16 bytes -> peel 2 + 4 + 4 + 2 (cached).
        float* po = outp + O_PLN + (size_t)oIdx*D_ + dbase;
        float a = istd[ii];
        float p[12];
#pragma unroll
        for (int m = 0; m < 12; m++) p[m] = (rw[m] - mu) * a * w_[m];
        *(float2*)po        = make_float2(p[0], p[1]);
        *(float4*)(po + 2)  = make_float4(p[2], p[3], p[4], p[5]);
        *(float4*)(po + 6)  = make_float4(p[6], p[7], p[8], p[9]);
        *(float2*)(po + 10) = make_float2(p[10], p[11]);
        smu[ii] += mu;
        if (isDiag) {
          // mixing excludes the diagonal: skip accS add; store the 3
          // preserving-norm scalars (ls2 = |diag s|^2, lrw2 = |diag rw|^2,
          // q = |w*(rw-mu)|^2 with istd factored out).
          if (lane == 0) {
            wsMui[b*S_ + iG] = mu;
            wsP[(b*S_ + iG)*3 + 0] = ls2;
            wsP[(b*S_ + iG)*3 + 1] = lrw2;
            wsP[(b*S_ + iG)*3 + 2] = q;
          }
        } else {
#pragma unroll
          for (int m = 0; m < 12; m++) accS[ii][m] += s[ii][m];
        }
      }
    }
  }

  // combine per-wave accumulators
  if (lane == 0) {
#pragma unroll
    for (int ii = 0; ii < I_T; ii++) sSmu[wv*I_T + ii] = smu[ii];
  }
  for (int rr = 0; rr < 12; rr++) {
    __syncthreads();
    if (wv == rr) {
#pragma unroll
      for (int ii = 0; ii < I_T; ii++) {
        if (ii < ni) {
#pragma unroll
          for (int m = 0; m < 12; m++) {
            int a = ii*D_ + dbase + m;
            sAcc[a] = (rr == 0) ? accS[ii][m] : (sAcc[a] + accS[ii][m]);
          }
        }
      }
    }
  }
  __syncthreads();
  if (tid < ni*192) {
    int ii = tid / 192; int d4 = (tid % 192) * 4;
    float4 v = *(float4*)&sAcc[ii*D_ + d4];
    *(float4*)(wsAccS + (size_t)((b*S_ + i0 + ii)*NC + c)*D_ + d4) = v;
  }
  if (tid < ni) {
    float ss = 0.f;
#pragma unroll
    for (int wq = 0; wq < 12; wq++) ss += sSmu[wq*I_T + tid];
    wsSmu[(b*S_ + i0 + tid)*NC + c] = ss;
  }
  // fused weighted_norm = |attn| * tnorm (all inputs in LDS)
  int totW = H_*ni*jcW;
  for (int e = tid; e < totW; e += 768) {
    int hh = e / (ni*jcW); int rem = e - hh*(ni*jcW);
    int ii = rem / jcW; int jj = rem - ii*jcW;
    int iG = i0 + ii;
    outp[O_WN + ((size_t)(b*H_ + hh)*S_ + iG)*S_ + jc0 + jj] =
        fabsf(ash[(hh*I_T + ii)*JC + jj]) * tnl[hh*JC + jj];
  }
}

// ------------- mixing-ratio finalization -------------
__global__ __launch_bounds__(256) void kMixing(const float* __restrict__ wsAccS,
                                               const float* __restrict__ wsSmu,
                                               const float* __restrict__ wsMui,
                                               const float* __restrict__ wsP,
                                               const float* __restrict__ lnw,
                                               float* __restrict__ outp) {
  int bi = blockIdx.x;   // b*197 + i
  int t = threadIdx.x;
  float Smu = wsSmu[bi*2] + wsSmu[bi*2 + 1];
  float mui = wsMui[bi];
  float dmu = Smu - mui;
  float mS = 0.f, mP = 0.f;
#pragma unroll
  for (int g = 0; g < 3; g++) {
    int d = t + g*256;
    float mix = wsAccS[((size_t)bi*2 + 0)*D_ + d] + wsAccS[((size_t)bi*2 + 1)*D_ + d];
    float w = lnw[d];
    mS = fmaf(mix, mix, mS);
    float mp = w * (mix - dmu);
    mP = fmaf(mp, mp, mP);
  }
  __shared__ float red[4][2];
  int lane = t & 63, wv = t >> 6;
  mS = wred64(mS); mP = wred64(mP);
  if (lane == 0) { red[wv][0] = mS; red[wv][1] = mP; }
  __syncthreads();
  if (t == 0) {
    float a0 = 0.f, a1 = 0.f;
#pragma unroll
    for (int k = 0; k < 4; k++) { a0 += red[k][0]; a1 += red[k][1]; }
    float mn = sqrtf(a0), mnp = sqrtf(a1);
    float pn   = sqrtf(wsP[bi*3 + 0]);
    float pnrw = sqrtf(wsP[bi*3 + 1]);
    float pnp  = sqrtf(wsP[bi*3 + 2]);
    outp[O_AM   + bi] = mn / (mn + pn);
    outp[O_ARM  + bi] = mn / (mn + pnrw);
    outp[O_ARLM + bi] = mnp / (mnp + pnp);
  }
}

extern "C" void kernel_launch(void* const* d_in, const int* in_sizes, int n_in,
                              void* d_out, int out_size, void* d_ws, size_t ws_size,
                              hipStream_t stream) {
  const float* hs    = (const float*)d_in[0];
  const float* attn  = (const float*)d_in[1];
  const float* V     = (const float*)d_in[2];
  const float* W     = (const float*)d_in[3];
  const float* lnw   = (const float*)d_in[4];
  const float* preln = (const float*)d_in[5];
  float* out = (float*)d_out;
  float* ws  = (float*)d_ws;

  kTranspose<<<dim3(24,24), dim3(32,8), 0, stream>>>(W, ws + WS_WT);
  kTransform<<<dim3(600), dim3(256), 0, stream>>>(V, ws + WS_WT, ws + WS_T2, ws + WS_TN);
  kMain<<<dim3(B_*NIT*NC), dim3(768), 0, stream>>>(attn, hs, lnw, preln, ws + WS_T2, ws + WS_TN,
                                                   out, ws + WS_ACC, ws + WS_SMU, ws + WS_MUI, ws + WS_P3);
  kMixing<<<dim3(B_*S_), dim3(256), 0, stream>>>(ws + WS_ACC, ws + WS_SMU, ws + WS_MUI, ws + WS_P3,
                                                 lnw, out);
}